// Round 8
// baseline (140.082 us; speedup 1.0000x reference)
//
#include <hip/hip_runtime.h>

typedef __bf16 bf16_t;
typedef bf16_t bf16x8 __attribute__((ext_vector_type(8)));
typedef bf16_t bf16x4 __attribute__((ext_vector_type(4)));
typedef float  floatx4 __attribute__((ext_vector_type(4)));

constexpr int Sq = 2048, Dq = 64;
constexpr int BQ = 128, BK = 64;
constexpr int NQT = Sq / BQ;      // 16 q-tiles of 128 rows
constexpr int STR = 72;           // padded LDS stride (16B-aligned rows)
constexpr float SCALE_LOG2E = 0.125f * 1.44269504088896340736f; // 1/8 * log2(e)

// r8: split-K flash attention with additive partials (fixed-max softmax makes
// O and l partials sum-combinable). 512 blocks = 32bh x 8 pairs{qt,15-qt} x 2
// k-halves; every block runs EXACTLY 17 k-iters (qt+1 + 16-qt) -> identical
// durations, no co-residency/dispatch assumptions (r7's failure mode). BQ=128
// register blocking kept: 32 MFMAs per wave-iter on the same LDS frag reads.
// Half 0 -> unnormalized O into d_out; half 1 -> output-shaped ws. Combine
// kernel: out = (O0 + O1) / (l0 + l1). XCD affinity via bh <-> b&7.
__global__ __launch_bounds__(256, 2) void flash_attn_splitk(
    const float* __restrict__ Q, const float* __restrict__ K,
    const float* __restrict__ V, float* __restrict__ O,
    float* __restrict__ wsO, float* __restrict__ wsLA, float* __restrict__ wsLB)
{
    __shared__ bf16_t QPs[BQ][STR];    // Q tile at start; then wave w's rows [32w,32w+32) = P buffer
    __shared__ bf16_t Ks[BK][STR];
    __shared__ bf16_t VTs[Dq][STR];    // V transposed: [d][j]

    const int tid  = threadIdx.x;
    const int wave = tid >> 6;
    const int lane = tid & 63;
    const int quad = lane >> 4;
    const int l16  = lane & 15;

    const int b    = blockIdx.x;
    const int half = b >> 8;           // k-range half
    const int x    = b & 255;
    const int bh   = (x & 7) | ((x >> 6) << 3);   // batch*head (low 3 bits -> XCD)
    const int pair = (x >> 3) & 7;
    const long base = (long)bh * Sq * Dq;

    float* __restrict__ dstO = half ? wsO  : O;    // both output-shaped
    float* __restrict__ wsL  = half ? wsLB : wsLA;

    const int r0 = tid >> 4;          // staging row-in-group
    const int c4 = (tid & 15) * 4;    // staging col
    const int h  = lane >> 3;         // V staging j-group stagger
    const int jw = wave * 16;

    for (int tt = 0; tt < 2; ++tt) {
        const int qt   = tt ? (NQT - 1 - pair) : pair;
        const int nkt  = qt + 1;           // this half's k-tile count (total 2qt+2)
        const int ktbeg = half * nkt;

        __syncthreads();   // prior tile's LDS reads fully done

        // ---- stage Q tile (128 rows, scaled, bf16) ----
        #pragma unroll
        for (int p = 0; p < 8; ++p) {
            const int row = p * 16 + r0;
            const float4 qv = *(const float4*)&Q[base + (long)(qt * BQ + row) * Dq + c4];
            bf16x4 w;
            w[0] = (bf16_t)(qv.x * SCALE_LOG2E); w[1] = (bf16_t)(qv.y * SCALE_LOG2E);
            w[2] = (bf16_t)(qv.z * SCALE_LOG2E); w[3] = (bf16_t)(qv.w * SCALE_LOG2E);
            *(bf16x4*)&QPs[row][c4] = w;
        }
        __syncthreads();

        // Q B-frags: q = 32*wave + u*16 + l16, d-halves hh (wave-private rows)
        bf16x8 aq[2][2];
        #pragma unroll
        for (int u = 0; u < 2; ++u)
            #pragma unroll
            for (int hh = 0; hh < 2; ++hh)
                aq[u][hh] = *(const bf16x8*)&QPs[32 * wave + u * 16 + l16][hh * 32 + quad * 8];

        float l_lane[2] = {0.f, 0.f};
        floatx4 o_acc[2][4];
        #pragma unroll
        for (int u = 0; u < 2; ++u)
            #pragma unroll
            for (int dt = 0; dt < 4; ++dt) o_acc[u][dt] = floatx4{0.f, 0.f, 0.f, 0.f};

        // ---- preload first k-tile of this half ----
        float4 kf[4];
        float  vf[4][4];
        {
            const long kb = base + (long)ktbeg * BK * Dq;
            #pragma unroll
            for (int p = 0; p < 4; ++p) {
                kf[p] = *(const float4*)&K[kb + (long)(p * 16 + r0) * Dq + c4];
                const int j0 = jw + 4 * ((p + h) & 3);
                #pragma unroll
                for (int r = 0; r < 4; ++r)
                    vf[p][r] = V[kb + (long)(j0 + r) * Dq + lane];
            }
        }

        for (int j = 0; j < nkt; ++j) {
            const int kt = ktbeg + j;
            __syncthreads();   // prior-iter LDS frag reads done

            // ---- registers -> LDS ----
            #pragma unroll
            for (int p = 0; p < 4; ++p) {
                bf16x4 w;
                w[0] = (bf16_t)kf[p].x; w[1] = (bf16_t)kf[p].y;
                w[2] = (bf16_t)kf[p].z; w[3] = (bf16_t)kf[p].w;
                *(bf16x4*)&Ks[p * 16 + r0][c4] = w;
                bf16x4 vw;
                vw[0] = (bf16_t)vf[p][0]; vw[1] = (bf16_t)vf[p][1];
                vw[2] = (bf16_t)vf[p][2]; vw[3] = (bf16_t)vf[p][3];
                *(bf16x4*)&VTs[lane][jw + 4 * ((p + h) & 3)] = vw;
            }
            __syncthreads();

            // ---- prefetch next k-tile (in flight across compute; L2-local) ----
            {
                const int kn = (j + 1 < nkt) ? (kt + 1) : kt;
                const long kb = base + (long)kn * BK * Dq;
                #pragma unroll
                for (int p = 0; p < 4; ++p) {
                    kf[p] = *(const float4*)&K[kb + (long)(p * 16 + r0) * Dq + c4];
                    const int j0 = jw + 4 * ((p + h) & 3);
                    #pragma unroll
                    for (int r = 0; r < 4; ++r)
                        vf[p][r] = V[kb + (long)(j0 + r) * Dq + lane];
                }
            }

            // ---- S^T = K * Q^T : acc[t][u] = S[k=64kt+16t+4quad+i][q=128qt+32w+16u+l16] ----
            floatx4 acc[4][2];
            #pragma unroll
            for (int t = 0; t < 4; ++t) {
                const int krow = t * 16 + l16;
                bf16x8 ak0 = *(const bf16x8*)&Ks[krow][quad * 8];
                bf16x8 ak1 = *(const bf16x8*)&Ks[krow][32 + quad * 8];
                #pragma unroll
                for (int u = 0; u < 2; ++u) {
                    acc[t][u] = floatx4{0.f, 0.f, 0.f, 0.f};
                    acc[t][u] = __builtin_amdgcn_mfma_f32_16x16x32_bf16(ak0, aq[u][0], acc[t][u], 0, 0, 0);
                    acc[t][u] = __builtin_amdgcn_mfma_f32_16x16x32_bf16(ak1, aq[u][1], acc[t][u], 0, 0, 0);
                }
            }

            // ---- causal mask (only k-tiles >= 2qt straddle the diagonal) ----
            if (kt >= 2 * qt) {
                #pragma unroll
                for (int u = 0; u < 2; ++u) {
                    const int qr = qt * BQ + 32 * wave + u * 16 + l16;
                    #pragma unroll
                    for (int t = 0; t < 4; ++t) {
                        #pragma unroll
                        for (int i = 0; i < 4; ++i) {
                            if (kt * BK + t * 16 + quad * 4 + i > qr) acc[t][u][i] = -1e30f;
                        }
                    }
                }
            }

            // ---- p = 2^s, accumulate partial denom ----
            #pragma unroll
            for (int u = 0; u < 2; ++u) {
                float l_add = 0.f;
                #pragma unroll
                for (int t = 0; t < 4; ++t) {
                    #pragma unroll
                    for (int i = 0; i < 4; ++i) {
                        acc[t][u][i] = __builtin_amdgcn_exp2f(acc[t][u][i]);
                        l_add += acc[t][u][i];
                    }
                }
                l_lane[u] += l_add;
            }

            // ---- P -> LDS in A-layout, b64-packed (wave-private rows) ----
            #pragma unroll
            for (int u = 0; u < 2; ++u) {
                #pragma unroll
                for (int t = 0; t < 4; ++t) {
                    bf16x4 pk;
                    pk[0] = (bf16_t)acc[t][u][0]; pk[1] = (bf16_t)acc[t][u][1];
                    pk[2] = (bf16_t)acc[t][u][2]; pk[3] = (bf16_t)acc[t][u][3];
                    *(bf16x4*)&QPs[32 * wave + u * 16 + l16][t * 16 + quad * 4] = pk;
                }
            }

            // ---- O += P V ----
            bf16x8 ap[2][2];
            #pragma unroll
            for (int u = 0; u < 2; ++u)
                #pragma unroll
                for (int hh = 0; hh < 2; ++hh)
                    ap[u][hh] = *(const bf16x8*)&QPs[32 * wave + u * 16 + l16][hh * 32 + quad * 8];
            #pragma unroll
            for (int dt = 0; dt < 4; ++dt) {
                const int dcol = dt * 16 + l16;
                bf16x8 bv0 = *(const bf16x8*)&VTs[dcol][quad * 8];
                bf16x8 bv1 = *(const bf16x8*)&VTs[dcol][32 + quad * 8];
                #pragma unroll
                for (int u = 0; u < 2; ++u) {
                    o_acc[u][dt] = __builtin_amdgcn_mfma_f32_16x16x32_bf16(ap[u][0], bv0, o_acc[u][dt], 0, 0, 0);
                    o_acc[u][dt] = __builtin_amdgcn_mfma_f32_16x16x32_bf16(ap[u][1], bv1, o_acc[u][dt], 0, 0, 0);
                }
            }
        }

        // ---- epilogue: write partial l and UNNORMALIZED partial O ----
        #pragma unroll
        for (int u = 0; u < 2; ++u) {
            float lsum = l_lane[u];
            lsum += __shfl_xor(lsum, 16);
            lsum += __shfl_xor(lsum, 32);   // full partial row-sum for q-row (u,l16)
            if (quad == 0) {
                wsL[(bh * NQT + qt) * BQ + 32 * wave + u * 16 + l16] = lsum;
            }
            #pragma unroll
            for (int i = 0; i < 4; ++i) {
                const long row = (long)qt * BQ + 32 * wave + u * 16 + quad * 4 + i;
                #pragma unroll
                for (int dt = 0; dt < 4; ++dt) {
                    dstO[base + row * Dq + dt * 16 + l16] = o_acc[u][dt][i];
                }
            }
        }
    }
}

__global__ __launch_bounds__(256) void combine_kernel(
    float* __restrict__ O, const float* __restrict__ wsO,
    const float* __restrict__ lA, const float* __restrict__ lB)
{
    const int g = blockIdx.x * 256 + threadIdx.x;   // float4 index
    const int row = g >> 4;                          // row == (bh*NQT+qt)*BQ + qr
    const float inv = 1.f / (lA[row] + lB[row]);
    const float4 a = ((const float4*)O)[g];
    const float4 c = ((const float4*)wsO)[g];
    float4 r;
    r.x = (a.x + c.x) * inv; r.y = (a.y + c.y) * inv;
    r.z = (a.z + c.z) * inv; r.w = (a.w + c.w) * inv;
    ((float4*)O)[g] = r;
}

extern "C" void kernel_launch(void* const* d_in, const int* in_sizes, int n_in,
                              void* d_out, int out_size, void* d_ws, size_t ws_size,
                              hipStream_t stream)
{
    const float* q = (const float*)d_in[0];
    const float* k = (const float*)d_in[1];
    const float* v = (const float*)d_in[2];
    float* out = (float*)d_out;
    // d_in[3] (mask) is the static causal mask; handled analytically in-kernel.
    // ws layout: O-partial (output-shaped, 4,194,304 f) | lA (65,536 f) | lB (65,536 f)
    float* wsO = (float*)d_ws;
    float* lA  = wsO + 4194304;
    float* lB  = lA + 65536;
    flash_attn_splitk<<<dim3(512, 1, 1), dim3(256, 1, 1), 0, stream>>>(q, k, v, out, wsO, lA, lB);
    combine_kernel<<<dim3(4096, 1, 1), dim3(256, 1, 1), 0, stream>>>(out, wsO, lA, lB);
}